// Round 6
// baseline (322.863 us; speedup 1.0000x reference)
//
#include <hip/hip_runtime.h>
#include <hip/hip_bf16.h>
#include <hip/hip_cooperative_groups.h>
#include <cstdint>

namespace cg = cooperative_groups;

// Problem: B=8, N=1024, C=256, H=8, D=64.
// out[b,i,o] = sum_{h,d} V[b,i,h,d] * w[b,i,h] * Wout[o,h,d]
// w[b,i,h]   = sum_j exp(S_ij)/d_j ;  S = Q K^T / 8 ; d_j = sum_i exp(S_ij)
// Scale fold: Wq' = Wq * 0.125*log2(e)  =>  exp(S/8) == exp2(Q'K^T).
//
// Five phases shared between (a) one cooperative fused kernel with
// grid.sync() and (b) a 5-kernel fallback if the coop launch errors.
// All phase LDS <= 31744 B so 512 blocks x 256 thr = 2 blocks/CU passes
// any occupancy validation.

typedef __attribute__((ext_vector_type(8))) short bf16x8;
typedef __attribute__((ext_vector_type(4))) float f32x4;

#if __has_builtin(__builtin_amdgcn_exp2f)
#define EXP2(x) __builtin_amdgcn_exp2f(x)
#else
#define EXP2(x) exp2f(x)
#endif

static __device__ __forceinline__ uint32_t pk2(float x, float y) {
  union { __hip_bfloat162 h; uint32_t u; } c;
  c.h = __float22bfloat162_rn(float2{x, y});
  return c.u;
}
static __device__ __forceinline__ short cvt1(float f) {
  union { __hip_bfloat16 h; short s; } c;
  c.h = __float2bfloat16(f);
  return c.s;
}
static __device__ __forceinline__ bf16x8 mk8(const float4& u, const float4& v) {
  union { bf16x8 b; uint32_t w[4]; } r;
  r.w[0] = pk2(u.x, u.y); r.w[1] = pk2(u.z, u.w);
  r.w[2] = pk2(v.x, v.y); r.w[3] = pk2(v.z, v.w);
  return r.b;
}

#define MFMA(a, b, c) __builtin_amdgcn_mfma_f32_16x16x32_bf16((a), (b), (c), 0, 0, 0)

#define NBLK 512

union SMem {
  struct { short Bs[3][64][72]; } qkv;                                 // 27648 B
  struct { short Ks[128][72]; short Qs[64][72]; } cs;                  // 27648 B
  struct { short Qs[128][72]; short Ks[64][72]; float Rs[1024]; } rs;  // 31744 B
  struct { short As[64][72]; short Bs[64][72]; } ko;                   // 18432 B
};

// ------------------------------------------------------------------ P0: prep
static __device__ __forceinline__ void phase_prep(int hw, int t,
    const float* Wq, const float* Wk, const float* Wv, const float* Wo,
    short* Wt, short* Wob)
{
  const int gt = hw * 256 + t;
  if (gt < 49152) {
    const int m  = gt >> 14;
    const int r  = gt & 16383;
    const int n  = r >> 5;
    const int c8 = r & 31;
    const float* W = (m == 0) ? Wq : (m == 1) ? Wk : Wv;
    const float scale = (m == 0) ? 0.18033688011112042f : 1.0f;
    short tmp[8];
#pragma unroll
    for (int j = 0; j < 8; ++j)
      tmp[j] = cvt1(W[(size_t)(c8 * 8 + j) * 512 + n] * scale);
    *(int4*)&Wt[(size_t)m * 131072 + n * 256 + c8 * 8] = *(int4*)tmp;
  } else if (gt < 65536) {
    const int r  = gt - 49152;
    const int o  = r >> 6;
    const int k8 = r & 63;
    const float4 v0 = *(const float4*)(Wo + (size_t)o * 512 + k8 * 8);
    const float4 v1 = *(const float4*)(Wo + (size_t)o * 512 + k8 * 8 + 4);
    uint32_t tmp[4] = {pk2(v0.x, v0.y), pk2(v0.z, v0.w),
                       pk2(v1.x, v1.y), pk2(v1.z, v1.w)};
    *(uint4*)&Wob[(size_t)o * 512 + k8 * 8] = *(uint4*)tmp;
  }
}

// ------------------------------------------------------------------ P1: qkv
static __device__ __forceinline__ void phase_qkv(SMem& sm, int hw, int t,
    const float* F, const short* Wt,
    short* Qh, short* Kh, short* Vh)
{
  const int slot = hw >> 3;
  const int g    = (hw & 7) * 8 + (slot >> 3);
  const int h    = slot & 7;
  const int mt   = g & 7;
  const int b    = g >> 3;
  const int n0   = h * 64;
  const int m0   = mt * 128;
  const int wv = t >> 6, l = t & 63, lo = l & 15, hi = l >> 4;

  int4   pb[6];
  float4 pa[8];
#pragma unroll
  for (int it = 0; it < 6; ++it) {
    int idx = t + it * 256, m = idx >> 9, rem = idx & 511, n = rem >> 3, c8 = rem & 7;
    pb[it] = *(const int4*)(Wt + ((size_t)m * 512 + n0 + n) * 256 + c8 * 8);
  }
#pragma unroll
  for (int fr = 0; fr < 2; ++fr) {
    const size_t row = (size_t)(b * 1024 + m0 + wv * 32 + fr * 16 + lo) * 256;
#pragma unroll
    for (int kk = 0; kk < 2; ++kk) {
      pa[(fr * 2 + kk) * 2 + 0] = *(const float4*)(F + row + kk * 32 + hi * 8);
      pa[(fr * 2 + kk) * 2 + 1] = *(const float4*)(F + row + kk * 32 + hi * 8 + 4);
    }
  }

  f32x4 acc[3][2][4];
#pragma unroll
  for (int m = 0; m < 3; ++m)
#pragma unroll
    for (int i = 0; i < 2; ++i)
#pragma unroll
      for (int j = 0; j < 4; ++j) acc[m][i][j] = (f32x4){0.f, 0.f, 0.f, 0.f};

  for (int s = 0; s < 4; ++s) {
    if (s) __syncthreads();
#pragma unroll
    for (int it = 0; it < 6; ++it) {
      int idx = t + it * 256, m = idx >> 9, rem = idx & 511, n = rem >> 3, c8 = rem & 7;
      *(int4*)&sm.qkv.Bs[m][n][c8 * 8] = pb[it];
    }
    __syncthreads();

    bf16x8 a[2][2];
#pragma unroll
    for (int fr = 0; fr < 2; ++fr)
#pragma unroll
      for (int kk = 0; kk < 2; ++kk)
        a[fr][kk] = mk8(pa[(fr * 2 + kk) * 2], pa[(fr * 2 + kk) * 2 + 1]);

    if (s < 3) {
      const int k0 = (s + 1) * 64;
#pragma unroll
      for (int it = 0; it < 6; ++it) {
        int idx = t + it * 256, m = idx >> 9, rem = idx & 511, n = rem >> 3, c8 = rem & 7;
        pb[it] = *(const int4*)(Wt + ((size_t)m * 512 + n0 + n) * 256 + k0 + c8 * 8);
      }
#pragma unroll
      for (int fr = 0; fr < 2; ++fr) {
        const size_t row = (size_t)(b * 1024 + m0 + wv * 32 + fr * 16 + lo) * 256;
#pragma unroll
        for (int kk = 0; kk < 2; ++kk) {
          pa[(fr * 2 + kk) * 2 + 0] = *(const float4*)(F + row + k0 + kk * 32 + hi * 8);
          pa[(fr * 2 + kk) * 2 + 1] = *(const float4*)(F + row + k0 + kk * 32 + hi * 8 + 4);
        }
      }
    }

#pragma unroll
    for (int m = 0; m < 3; ++m)
#pragma unroll
      for (int kk = 0; kk < 2; ++kk)
#pragma unroll
        for (int fc = 0; fc < 4; ++fc) {
          bf16x8 bfr = *(const bf16x8*)&sm.qkv.Bs[m][fc * 16 + lo][kk * 32 + hi * 8];
#pragma unroll
          for (int fr = 0; fr < 2; ++fr)
            acc[m][fr][fc] = MFMA(a[fr][kk], bfr, acc[m][fr][fc]);
        }
  }

#pragma unroll
  for (int m = 0; m < 3; ++m) {
    short* O = (m == 0) ? Qh : (m == 1) ? Kh : Vh;
#pragma unroll
    for (int fr = 0; fr < 2; ++fr)
#pragma unroll
      for (int fc = 0; fc < 4; ++fc)
#pragma unroll
        for (int r = 0; r < 4; ++r) {
          int i = m0 + wv * 32 + fr * 16 + hi * 4 + r;
          int d = fc * 16 + lo;
          O[((size_t)(b * 8 + h) * 1024 + i) * 64 + d] = cvt1(acc[m][fr][fc][r]);
        }
  }
}

// ------------------------------------------------------------------ P2: colsum
static __device__ __forceinline__ void phase_colsum(SMem& sm, int hw, int t,
    const short* Qh, const short* Kh, float* Dd)
{
  const int slot = hw >> 3;
  const int g    = (hw & 7) * 8 + (slot >> 3);
  const int jb   = slot & 7;
  const int b    = g >> 3;
  const int h    = g & 7;
  const size_t base = (size_t)(b * 8 + h) * 65536;
  const int j0   = jb * 128;
  const int wv = t >> 6, l = t & 63, lo = l & 15, hi = l >> 4;

#pragma unroll
  for (int it = 0; it < 4; ++it) {
    int idx = t + it * 256, r = idx >> 3, c8 = idx & 7;
    *(int4*)&sm.cs.Ks[r][c8 * 8] =
        *(const int4*)(Kh + base + (size_t)(j0 + r) * 64 + c8 * 8);
  }
  int4 pq[2];
#pragma unroll
  for (int it = 0; it < 2; ++it) {
    int idx = t + it * 256, r = idx >> 3, c8 = idx & 7;
    pq[it] = *(const int4*)(Qh + base + (size_t)r * 64 + c8 * 8);
  }
  __syncthreads();

  bf16x8 bk[2][2];
#pragma unroll
  for (int js = 0; js < 2; ++js)
#pragma unroll
    for (int kk = 0; kk < 2; ++kk)
      bk[js][kk] = *(const bf16x8*)&sm.cs.Ks[wv * 32 + js * 16 + lo][kk * 32 + hi * 8];

  float cs2[2] = {0.f, 0.f};
  for (int tile = 0; tile < 16; ++tile) {
    if (tile) __syncthreads();
#pragma unroll
    for (int it = 0; it < 2; ++it) {
      int idx = t + it * 256, r = idx >> 3, c8 = idx & 7;
      *(int4*)&sm.cs.Qs[r][c8 * 8] = pq[it];
    }
    __syncthreads();
    if (tile < 15) {
#pragma unroll
      for (int it = 0; it < 2; ++it) {
        int idx = t + it * 256, r = idx >> 3, c8 = idx & 7;
        pq[it] = *(const int4*)(Qh + base + (size_t)((tile + 1) * 64 + r) * 64 + c8 * 8);
      }
    }
#pragma unroll
    for (int f = 0; f < 4; ++f) {
      bf16x8 a0 = *(const bf16x8*)&sm.cs.Qs[f * 16 + lo][hi * 8];
      bf16x8 a1 = *(const bf16x8*)&sm.cs.Qs[f * 16 + lo][32 + hi * 8];
#pragma unroll
      for (int js = 0; js < 2; ++js) {
        f32x4 acc = (f32x4){0.f, 0.f, 0.f, 0.f};
        acc = MFMA(a0, bk[js][0], acc);
        acc = MFMA(a1, bk[js][1], acc);
#pragma unroll
        for (int r = 0; r < 4; ++r) cs2[js] += EXP2(acc[r]);
      }
    }
  }

#pragma unroll
  for (int js = 0; js < 2; ++js) {
    cs2[js] += __shfl_xor(cs2[js], 16, 64);
    cs2[js] += __shfl_xor(cs2[js], 32, 64);
  }
  if (hi == 0) {
    Dd[(size_t)(b * 8 + h) * 1024 + j0 + wv * 32 + lo]      = cs2[0];
    Dd[(size_t)(b * 8 + h) * 1024 + j0 + wv * 32 + 16 + lo] = cs2[1];
  }
}

// ------------------------------------------------------------------ P3: rowsum
static __device__ __forceinline__ void phase_rowsum(SMem& sm, int hw, int t,
    const short* Qh, const short* Kh, const float* Dd, float* Wg2)
{
  const int slot = hw >> 3;
  const int g    = (hw & 7) * 8 + (slot >> 3);
  const int ib   = slot & 7;
  const int b    = g >> 3;
  const int h    = g & 7;
  const size_t base = (size_t)(b * 8 + h) * 65536;
  const int i0   = ib * 128;
  const int wv = t >> 6, l = t & 63, lo = l & 15, hi = l >> 4;

  {
    const float4 dv = *(const float4*)(Dd + (size_t)(b * 8 + h) * 1024 + t * 4);
    sm.rs.Rs[t * 4 + 0] = __builtin_amdgcn_rcpf(dv.x);
    sm.rs.Rs[t * 4 + 1] = __builtin_amdgcn_rcpf(dv.y);
    sm.rs.Rs[t * 4 + 2] = __builtin_amdgcn_rcpf(dv.z);
    sm.rs.Rs[t * 4 + 3] = __builtin_amdgcn_rcpf(dv.w);
  }
#pragma unroll
  for (int it = 0; it < 4; ++it) {
    int idx = t + it * 256, r = idx >> 3, c8 = idx & 7;
    *(int4*)&sm.rs.Qs[r][c8 * 8] =
        *(const int4*)(Qh + base + (size_t)(i0 + r) * 64 + c8 * 8);
  }
  int4 pk[2];
#pragma unroll
  for (int it = 0; it < 2; ++it) {
    int idx = t + it * 256, r = idx >> 3, c8 = idx & 7;
    pk[it] = *(const int4*)(Kh + base + (size_t)r * 64 + c8 * 8);
  }
  __syncthreads();

  bf16x8 aq[2][2];
#pragma unroll
  for (int is = 0; is < 2; ++is)
#pragma unroll
    for (int kk = 0; kk < 2; ++kk)
      aq[is][kk] = *(const bf16x8*)&sm.rs.Qs[wv * 32 + is * 16 + lo][kk * 32 + hi * 8];

  float wa[2][4] = {{0.f, 0.f, 0.f, 0.f}, {0.f, 0.f, 0.f, 0.f}};
  for (int tile = 0; tile < 16; ++tile) {
    if (tile) __syncthreads();
#pragma unroll
    for (int it = 0; it < 2; ++it) {
      int idx = t + it * 256, r = idx >> 3, c8 = idx & 7;
      *(int4*)&sm.rs.Ks[r][c8 * 8] = pk[it];
    }
    __syncthreads();
    if (tile < 15) {
#pragma unroll
      for (int it = 0; it < 2; ++it) {
        int idx = t + it * 256, r = idx >> 3, c8 = idx & 7;
        pk[it] = *(const int4*)(Kh + base + (size_t)((tile + 1) * 64 + r) * 64 + c8 * 8);
      }
    }
#pragma unroll
    for (int f = 0; f < 4; ++f) {
      bf16x8 b0 = *(const bf16x8*)&sm.rs.Ks[f * 16 + lo][hi * 8];
      bf16x8 b1 = *(const bf16x8*)&sm.rs.Ks[f * 16 + lo][32 + hi * 8];
      float rj = sm.rs.Rs[tile * 64 + f * 16 + lo];
#pragma unroll
      for (int is = 0; is < 2; ++is) {
        f32x4 acc = (f32x4){0.f, 0.f, 0.f, 0.f};
        acc = MFMA(aq[is][0], b0, acc);
        acc = MFMA(aq[is][1], b1, acc);
#pragma unroll
        for (int r = 0; r < 4; ++r) wa[is][r] = fmaf(EXP2(acc[r]), rj, wa[is][r]);
      }
    }
  }

#pragma unroll
  for (int m = 1; m <= 8; m <<= 1)
#pragma unroll
    for (int is = 0; is < 2; ++is)
#pragma unroll
      for (int r = 0; r < 4; ++r) wa[is][r] += __shfl_xor(wa[is][r], m, 64);

  if (lo == 0) {
#pragma unroll
    for (int is = 0; is < 2; ++is) {
      float4 o = {wa[is][0], wa[is][1], wa[is][2], wa[is][3]};
      *(float4*)&Wg2[(size_t)(b * 8 + h) * 1024 + i0 + wv * 32 + is * 16 + hi * 4] = o;
    }
  }
}

// ------------------------------------------------------------------ P4: out
static __device__ __forceinline__ void phase_out(SMem& sm, int hw, int t,
    const short* Vh, const float* Wg2, const short* Wob, float* Out)
{
  const int slot = hw >> 3;
  const int g    = (hw & 7) * 16 + (slot >> 2);
  const int nt   = slot & 3;
  const int b    = g >> 4;
  const int mt   = g & 15;
  const int n0   = nt * 64;
  const int m0   = mt * 64;
  const int wv = t >> 6, l = t & 63, lo = l & 15, hi = l >> 4;

  int4  pv[2], pbb[2];
  float pw[2];
#pragma unroll
  for (int it = 0; it < 2; ++it) {
    int idx = t + it * 256, r = idx >> 3, c8 = idx & 7;
    pv[it]  = *(const int4*)(Vh + ((size_t)(b * 8 + 0) * 1024 + m0 + r) * 64 + c8 * 8);
    pw[it]  = Wg2[(size_t)(b * 8 + 0) * 1024 + m0 + r];
    pbb[it] = *(const int4*)(Wob + (size_t)(n0 + r) * 512 + 0 * 64 + c8 * 8);
  }

  f32x4 acc[4];
#pragma unroll
  for (int j = 0; j < 4; ++j) acc[j] = (f32x4){0.f, 0.f, 0.f, 0.f};

  for (int s = 0; s < 8; ++s) {
    if (s) __syncthreads();
#pragma unroll
    for (int it = 0; it < 2; ++it) {
      int idx = t + it * 256, r = idx >> 3, c8 = idx & 7;
      uint32_t* u = (uint32_t*)&pv[it];
      float ws = pw[it];
      uint32_t o[4];
#pragma unroll
      for (int j = 0; j < 4; ++j) {
        float f0 = __uint_as_float(u[j] << 16) * ws;
        float f1 = __uint_as_float(u[j] & 0xffff0000u) * ws;
        o[j] = pk2(f0, f1);
      }
      *(uint4*)&sm.ko.As[r][c8 * 8] = *(uint4*)o;
      *(int4*)&sm.ko.Bs[r][c8 * 8]  = pbb[it];
    }
    __syncthreads();
    if (s < 7) {
#pragma unroll
      for (int it = 0; it < 2; ++it) {
        int idx = t + it * 256, r = idx >> 3, c8 = idx & 7;
        pv[it]  = *(const int4*)(Vh + ((size_t)(b * 8 + s + 1) * 1024 + m0 + r) * 64 + c8 * 8);
        pw[it]  = Wg2[(size_t)(b * 8 + s + 1) * 1024 + m0 + r];
        pbb[it] = *(const int4*)(Wob + (size_t)(n0 + r) * 512 + (s + 1) * 64 + c8 * 8);
      }
    }

#pragma unroll
    for (int kk = 0; kk < 2; ++kk) {
      bf16x8 a = *(const bf16x8*)&sm.ko.As[wv * 16 + lo][kk * 32 + hi * 8];
#pragma unroll
      for (int fc = 0; fc < 4; ++fc) {
        bf16x8 bfr = *(const bf16x8*)&sm.ko.Bs[fc * 16 + lo][kk * 32 + hi * 8];
        acc[fc] = MFMA(a, bfr, acc[fc]);
      }
    }
  }

#pragma unroll
  for (int fc = 0; fc < 4; ++fc)
#pragma unroll
    for (int r = 0; r < 4; ++r) {
      int i = m0 + wv * 16 + hi * 4 + r;
      int o = n0 + fc * 16 + lo;
      Out[(size_t)(b * 1024 + i) * 256 + o] = acc[fc][r];
    }
}

// ------------------------------------------------------------------ fused
__global__ __launch_bounds__(256, 2) void k_fused(
    const float* __restrict__ F,  const float* __restrict__ Wq,
    const float* __restrict__ Wk, const float* __restrict__ Wv,
    const float* __restrict__ Wo,
    short* __restrict__ Qh, short* __restrict__ Kh, short* __restrict__ Vh,
    float* __restrict__ Dd, float* __restrict__ Wg2,
    short* __restrict__ Wt, short* __restrict__ Wob,
    float* __restrict__ Out)
{
  cg::grid_group grid = cg::this_grid();
  __shared__ SMem sm;
  const int hw = blockIdx.x;
  const int t  = threadIdx.x;

  phase_prep(hw, t, Wq, Wk, Wv, Wo, Wt, Wob);
  grid.sync();
  phase_qkv(sm, hw, t, F, Wt, Qh, Kh, Vh);
  grid.sync();
  phase_colsum(sm, hw, t, Qh, Kh, Dd);
  grid.sync();
  phase_rowsum(sm, hw, t, Qh, Kh, Dd, Wg2);
  grid.sync();
  phase_out(sm, hw, t, Vh, Wg2, Wob, Out);
}

// ------------------------------------------------------------------ fallback wrappers
__global__ __launch_bounds__(256, 2) void k_p0(
    const float* Wq, const float* Wk, const float* Wv, const float* Wo,
    short* Wt, short* Wob)
{ phase_prep(blockIdx.x, threadIdx.x, Wq, Wk, Wv, Wo, Wt, Wob); }

__global__ __launch_bounds__(256, 2) void k_p1(
    const float* F, const short* Wt, short* Qh, short* Kh, short* Vh)
{ __shared__ SMem sm; phase_qkv(sm, blockIdx.x, threadIdx.x, F, Wt, Qh, Kh, Vh); }

__global__ __launch_bounds__(256, 2) void k_p2(
    const short* Qh, const short* Kh, float* Dd)
{ __shared__ SMem sm; phase_colsum(sm, blockIdx.x, threadIdx.x, Qh, Kh, Dd); }

__global__ __launch_bounds__(256, 2) void k_p3(
    const short* Qh, const short* Kh, const float* Dd, float* Wg2)
{ __shared__ SMem sm; phase_rowsum(sm, blockIdx.x, threadIdx.x, Qh, Kh, Dd, Wg2); }

__global__ __launch_bounds__(256, 2) void k_p4(
    const short* Vh, const float* Wg2, const short* Wob, float* Out)
{ __shared__ SMem sm; phase_out(sm, blockIdx.x, threadIdx.x, Vh, Wg2, Wob, Out); }

// ---------------------------------------------------------------------------
extern "C" void kernel_launch(void* const* d_in, const int* in_sizes, int n_in,
                              void* d_out, int out_size, void* d_ws, size_t ws_size,
                              hipStream_t stream) {
  const float* F  = (const float*)d_in[0];
  const float* Wq = (const float*)d_in[1];
  const float* Wk = (const float*)d_in[2];
  const float* Wv = (const float*)d_in[3];
  const float* Wo = (const float*)d_in[4];
  float* out = (float*)d_out;

  char* ws = (char*)d_ws;
  short* Qh  = (short*)(ws);                                     // 8 MB
  short* Kh  = (short*)(ws + (size_t)(8  << 20));                // 8 MB
  short* Vh  = (short*)(ws + (size_t)(16 << 20));                // 8 MB
  float* Dd  = (float*)(ws + (size_t)(24 << 20));                // 256 KB
  float* Wg2 = (float*)(ws + (size_t)(24 << 20) + (256 << 10));  // 256 KB
  short* Wt  = (short*)(ws + (size_t)(24 << 20) + (512 << 10));  // 768 KB
  short* Wob = (short*)(ws + (size_t)(24 << 20) + (1280 << 10)); // 256 KB

  void* args[] = {
    (void*)&F, (void*)&Wq, (void*)&Wk, (void*)&Wv, (void*)&Wo,
    (void*)&Qh, (void*)&Kh, (void*)&Vh, (void*)&Dd, (void*)&Wg2,
    (void*)&Wt, (void*)&Wob, (void*)&out
  };
  hipError_t st = hipLaunchCooperativeKernel((const void*)k_fused,
                                             dim3(NBLK), dim3(256),
                                             args, 0, stream);
  if (st != hipSuccess) {
    (void)hipGetLastError();  // clear the sticky error; use fallback path
    k_p0<<<dim3(NBLK), 256, 0, stream>>>(Wq, Wk, Wv, Wo, Wt, Wob);
    k_p1<<<dim3(NBLK), 256, 0, stream>>>(F, Wt, Qh, Kh, Vh);
    k_p2<<<dim3(NBLK), 256, 0, stream>>>(Qh, Kh, Dd);
    k_p3<<<dim3(NBLK), 256, 0, stream>>>(Qh, Kh, Dd, Wg2);
    k_p4<<<dim3(NBLK), 256, 0, stream>>>(Vh, Wg2, Wob, out);
  }
}

// Round 7
// 96.298 us; speedup vs baseline: 3.3528x; 3.3528x over previous
//
#include <hip/hip_runtime.h>
#include <hip/hip_bf16.h>
#include <cstdint>

// Problem: B=8, N=1024, C=256, H=8, D=64.
// out[b,i,o] = sum_{h,d} V[b,i,h,d] * w[b,i,h] * Wout[o,h,d]
// w[b,i,h]   = sum_j exp(S_ij)/d_j ;  S = Q K^T / 8 ; d_j = sum_i exp(S_ij)
// Q stored pre-scaled by 0.125*log2(e) => exp(S/8) == exp2(Q'K^T).
//
// 3 kernels: k_qkv (inline weight cvt), k_attw (colsum+rowsum fused,
// K-resident-in-registers 8 strips/wave, d_j block-local), k_out (inline
// Wo cvt + partial-w sum). Layouts: Qh/Kh/Vh=[b][h][i][d] bf16;
// Wgp=[jb=8][b*8+h][i] f32 partial row-weights.

typedef __attribute__((ext_vector_type(8))) short bf16x8;
typedef __attribute__((ext_vector_type(4))) float f32x4;

#define EXP2(x) __builtin_amdgcn_exp2f(x)
#define MFMA(a, b, c) __builtin_amdgcn_mfma_f32_16x16x32_bf16((a), (b), (c), 0, 0, 0)
#define QSCALE 0.18033688011112042f

static __device__ __forceinline__ uint32_t pk2(float x, float y) {
  union { __hip_bfloat162 h; uint32_t u; } c;
  c.h = __float22bfloat162_rn(float2{x, y});
  return c.u;
}
static __device__ __forceinline__ short cvt1(float f) {
  union { __hip_bfloat16 h; short s; } c;
  c.h = __float2bfloat16(f);
  return c.s;
}
static __device__ __forceinline__ bf16x8 mk8(const float4& u, const float4& v) {
  union { bf16x8 b; uint32_t w[4]; } r;
  r.w[0] = pk2(u.x, u.y); r.w[1] = pk2(u.z, u.w);
  r.w[2] = pk2(v.x, v.y); r.w[3] = pk2(v.z, v.w);
  return r.b;
}

// ---------------------------------------------------------------------------
// K1: fused QKV projection, inline weight conversion. 512 blocks x 256.
// Block: (b, mt of 128 rows, head h). Per k-step: A from global->regs,
// B converted fp32->bf16 at staging (coalesced along-n reads).
// ---------------------------------------------------------------------------
__global__ __launch_bounds__(256, 2) void k_qkv(
    const float* __restrict__ F,  const float* __restrict__ Wq,
    const float* __restrict__ Wk, const float* __restrict__ Wv,
    short* __restrict__ Qh, short* __restrict__ Kh, short* __restrict__ Vh)
{
  __shared__ short Bs[3][64][72];
  const int hw = blockIdx.x, t = threadIdx.x;
  const int slot = hw >> 3;
  const int g    = (hw & 7) * 8 + (slot >> 3);
  const int h    = slot & 7;
  const int mt   = g & 7;
  const int b    = g >> 3;
  const int n0   = h * 64;
  const int m0   = mt * 128;
  const int wv = t >> 6, l = t & 63, lo = l & 15, hi = l >> 4;

  // B prefetch (step 0), converted to packed bf16 pairs.
  // idx = t+it*256 in [0,1536): m=idx>>9, rem=idx&511, c8=rem>>6, n=rem&63.
  uint32_t pbp[6][4];
#pragma unroll
  for (int it = 0; it < 6; ++it) {
    int idx = t + it * 256, m = idx >> 9, rem = idx & 511, c8 = rem >> 6, n = rem & 63;
    const float* W = (m == 0) ? Wq : (m == 1) ? Wk : Wv;
    float f[8];
#pragma unroll
    for (int j = 0; j < 8; ++j) f[j] = W[(size_t)(c8 * 8 + j) * 512 + n0 + n];
#pragma unroll
    for (int q = 0; q < 4; ++q) pbp[it][q] = pk2(f[2 * q], f[2 * q + 1]);
  }
  // A prefetch (step 0): each lane's own fragment rows.
  float4 pa[8];
#pragma unroll
  for (int fr = 0; fr < 2; ++fr) {
    const size_t row = (size_t)(b * 1024 + m0 + wv * 32 + fr * 16 + lo) * 256;
#pragma unroll
    for (int kk = 0; kk < 2; ++kk) {
      pa[(fr * 2 + kk) * 2 + 0] = *(const float4*)(F + row + kk * 32 + hi * 8);
      pa[(fr * 2 + kk) * 2 + 1] = *(const float4*)(F + row + kk * 32 + hi * 8 + 4);
    }
  }

  f32x4 acc[3][2][4];
#pragma unroll
  for (int m = 0; m < 3; ++m)
#pragma unroll
    for (int i = 0; i < 2; ++i)
#pragma unroll
      for (int j = 0; j < 4; ++j) acc[m][i][j] = (f32x4){0.f, 0.f, 0.f, 0.f};

  for (int s = 0; s < 4; ++s) {
    if (s) __syncthreads();
#pragma unroll
    for (int it = 0; it < 6; ++it) {
      int idx = t + it * 256, m = idx >> 9, rem = idx & 511, c8 = rem >> 6, n = rem & 63;
      *(uint4*)&Bs[m][n][c8 * 8] = *(uint4*)pbp[it];
    }
    __syncthreads();

    bf16x8 a[2][2];
#pragma unroll
    for (int fr = 0; fr < 2; ++fr)
#pragma unroll
      for (int kk = 0; kk < 2; ++kk)
        a[fr][kk] = mk8(pa[(fr * 2 + kk) * 2], pa[(fr * 2 + kk) * 2 + 1]);

    if (s < 3) {
      const int k0 = (s + 1) * 64;
#pragma unroll
      for (int fr = 0; fr < 2; ++fr) {
        const size_t row = (size_t)(b * 1024 + m0 + wv * 32 + fr * 16 + lo) * 256;
#pragma unroll
        for (int kk = 0; kk < 2; ++kk) {
          pa[(fr * 2 + kk) * 2 + 0] = *(const float4*)(F + row + k0 + kk * 32 + hi * 8);
          pa[(fr * 2 + kk) * 2 + 1] = *(const float4*)(F + row + k0 + kk * 32 + hi * 8 + 4);
        }
      }
#pragma unroll
      for (int it = 0; it < 6; ++it) {
        int idx = t + it * 256, m = idx >> 9, rem = idx & 511, c8 = rem >> 6, n = rem & 63;
        const float* W = (m == 0) ? Wq : (m == 1) ? Wk : Wv;
        float f[8];
#pragma unroll
        for (int j = 0; j < 8; ++j) f[j] = W[(size_t)(k0 + c8 * 8 + j) * 512 + n0 + n];
#pragma unroll
        for (int q = 0; q < 4; ++q) pbp[it][q] = pk2(f[2 * q], f[2 * q + 1]);
      }
    }

#pragma unroll
    for (int m = 0; m < 3; ++m)
#pragma unroll
      for (int kk = 0; kk < 2; ++kk)
#pragma unroll
        for (int fc = 0; fc < 4; ++fc) {
          bf16x8 bfr = *(const bf16x8*)&Bs[m][fc * 16 + lo][kk * 32 + hi * 8];
#pragma unroll
          for (int fr = 0; fr < 2; ++fr)
            acc[m][fr][fc] = MFMA(a[fr][kk], bfr, acc[m][fr][fc]);
        }
  }

#pragma unroll
  for (int m = 0; m < 3; ++m) {
    short* O = (m == 0) ? Qh : (m == 1) ? Kh : Vh;
#pragma unroll
    for (int fr = 0; fr < 2; ++fr)
#pragma unroll
      for (int fc = 0; fc < 4; ++fc)
#pragma unroll
        for (int r = 0; r < 4; ++r) {
          int i = m0 + wv * 32 + fr * 16 + hi * 4 + r;
          int d = fc * 16 + lo;
          float v = acc[m][fr][fc][r];
          if (m == 0) v *= QSCALE;  // fold softmax scale into stored Q
          O[((size_t)(b * 8 + h) * 1024 + i) * 64 + d] = cvt1(v);
        }
  }
}

// ---------------------------------------------------------------------------
// K2: fused colsum+rowsum. 512 blocks x 256 = (b,h) x 8 jb-slices of 128 j.
// K-slice resident in registers (8 strips of 16 per wave). Pass 1: d_j for
// the block's j-range (column sums are j-local). Pass 2: partial w_i over
// this j-range -> Wgp[jb][bh][i].
// ---------------------------------------------------------------------------
__global__ __launch_bounds__(256, 2) void k_attw(
    const short* __restrict__ Qh, const short* __restrict__ Kh,
    float* __restrict__ Wgp)
{
  __shared__ short Ks[128][72];
  __shared__ short Qs[64][72];
  __shared__ float Red[512];
  const int hw = blockIdx.x, t = threadIdx.x;
  const int slot = hw >> 3;
  const int g    = (hw & 7) * 8 + (slot >> 3);
  const int jb   = slot & 7;
  const int b    = g >> 3;
  const int h    = g & 7;
  const size_t base = (size_t)(b * 8 + h) * 65536;
  const int j0   = jb * 128;
  const int wv = t >> 6, l = t & 63, lo = l & 15, hi = l >> 4;

  // stage resident K slice (128 x 64)
#pragma unroll
  for (int it = 0; it < 4; ++it) {
    int idx = t + it * 256, r = idx >> 3, c8 = idx & 7;
    *(int4*)&Ks[r][c8 * 8] = *(const int4*)(Kh + base + (size_t)(j0 + r) * 64 + c8 * 8);
  }
  int4 pq[2];
#pragma unroll
  for (int it = 0; it < 2; ++it) {
    int idx = t + it * 256, r = idx >> 3, c8 = idx & 7;
    pq[it] = *(const int4*)(Qh + base + (size_t)r * 64 + c8 * 8);
  }
  __syncthreads();

  // all 8 j-strips resident per wave: 64 VGPR
  bf16x8 bk[8][2];
#pragma unroll
  for (int js = 0; js < 8; ++js)
#pragma unroll
    for (int kk = 0; kk < 2; ++kk)
      bk[js][kk] = *(const bf16x8*)&Ks[js * 16 + lo][kk * 32 + hi * 8];

  // -------- pass 1: d_j = sum_i exp2(S'_ij), i streamed; waves split rows
  float cs[8];
#pragma unroll
  for (int js = 0; js < 8; ++js) cs[js] = 0.f;

  for (int tile = 0; tile < 16; ++tile) {
    if (tile) __syncthreads();
#pragma unroll
    for (int it = 0; it < 2; ++it) {
      int idx = t + it * 256, r = idx >> 3, c8 = idx & 7;
      *(int4*)&Qs[r][c8 * 8] = pq[it];
    }
    __syncthreads();
    if (tile < 15) {
#pragma unroll
      for (int it = 0; it < 2; ++it) {
        int idx = t + it * 256, r = idx >> 3, c8 = idx & 7;
        pq[it] = *(const int4*)(Qh + base + (size_t)((tile + 1) * 64 + r) * 64 + c8 * 8);
      }
    }
    bf16x8 a0 = *(const bf16x8*)&Qs[wv * 16 + lo][hi * 8];
    bf16x8 a1 = *(const bf16x8*)&Qs[wv * 16 + lo][32 + hi * 8];
#pragma unroll
    for (int js = 0; js < 8; ++js) {
      f32x4 acc = (f32x4){0.f, 0.f, 0.f, 0.f};
      acc = MFMA(a0, bk[js][0], acc);
      acc = MFMA(a1, bk[js][1], acc);
#pragma unroll
      for (int r = 0; r < 4; ++r) cs[js] += EXP2(acc[r]);
    }
  }

  // reduce within wave (over i-rows held across hi groups)...
#pragma unroll
  for (int js = 0; js < 8; ++js) {
    cs[js] += __shfl_xor(cs[js], 16, 64);
    cs[js] += __shfl_xor(cs[js], 32, 64);
  }
  // ...then across the 4 waves via LDS
  if (hi == 0) {
#pragma unroll
    for (int js = 0; js < 8; ++js) Red[wv * 128 + js * 16 + lo] = cs[js];
  }
  __syncthreads();
  float rj[8];
#pragma unroll
  for (int js = 0; js < 8; ++js) {
    int jj = js * 16 + lo;
    float d = Red[jj] + Red[128 + jj] + Red[256 + jj] + Red[384 + jj];
    rj[js] = __builtin_amdgcn_rcpf(d);
  }

  // -------- pass 2: partial w_i = sum_{j in block} exp2(S'_ij) / d_j
#pragma unroll
  for (int it = 0; it < 2; ++it) {
    int idx = t + it * 256, r = idx >> 3, c8 = idx & 7;
    pq[it] = *(const int4*)(Qh + base + (size_t)r * 64 + c8 * 8);
  }
  for (int tile = 0; tile < 16; ++tile) {
    if (tile) __syncthreads();
#pragma unroll
    for (int it = 0; it < 2; ++it) {
      int idx = t + it * 256, r = idx >> 3, c8 = idx & 7;
      *(int4*)&Qs[r][c8 * 8] = pq[it];
    }
    __syncthreads();
    if (tile < 15) {
#pragma unroll
      for (int it = 0; it < 2; ++it) {
        int idx = t + it * 256, r = idx >> 3, c8 = idx & 7;
        pq[it] = *(const int4*)(Qh + base + (size_t)((tile + 1) * 64 + r) * 64 + c8 * 8);
      }
    }
    bf16x8 a0 = *(const bf16x8*)&Qs[wv * 16 + lo][hi * 8];
    bf16x8 a1 = *(const bf16x8*)&Qs[wv * 16 + lo][32 + hi * 8];
    float ws4[4] = {0.f, 0.f, 0.f, 0.f};
#pragma unroll
    for (int js = 0; js < 8; ++js) {
      f32x4 acc = (f32x4){0.f, 0.f, 0.f, 0.f};
      acc = MFMA(a0, bk[js][0], acc);
      acc = MFMA(a1, bk[js][1], acc);
#pragma unroll
      for (int r = 0; r < 4; ++r) ws4[r] = fmaf(EXP2(acc[r]), rj[js], ws4[r]);
    }
    // reduce over the 16 j-columns held across lo lanes
#pragma unroll
    for (int m = 1; m <= 8; m <<= 1)
#pragma unroll
      for (int r = 0; r < 4; ++r) ws4[r] += __shfl_xor(ws4[r], m, 64);
    if (lo == 0) {
      float4 o = {ws4[0], ws4[1], ws4[2], ws4[3]};
      *(float4*)&Wgp[(size_t)jb * 65536 + (size_t)(b * 8 + h) * 1024 +
                     tile * 64 + wv * 16 + hi * 4] = o;
    }
  }
}

// ---------------------------------------------------------------------------
// K3: out = (V .* w) @ Wo^T, w = sum of 8 jb-partials. Inline Wo conversion.
// 512 blocks x 256; M-tile 64, N-tile 64, K-step 64 (= head s).
// ---------------------------------------------------------------------------
__global__ __launch_bounds__(256, 2) void k_out(
    const short* __restrict__ Vh, const float* __restrict__ Wgp,
    const float* __restrict__ Wo, float* __restrict__ Out)
{
  __shared__ short As[64][72];
  __shared__ short Bs[64][72];
  const int hw = blockIdx.x, t = threadIdx.x;
  const int slot = hw >> 3;
  const int g    = (hw & 7) * 16 + (slot >> 2);
  const int nt   = slot & 3;
  const int b    = g >> 4;
  const int mt   = g & 15;
  const int n0   = nt * 64;
  const int m0   = mt * 64;
  const int wv = t >> 6, l = t & 63, lo = l & 15, hi = l >> 4;

  int4     pv[2];
  float    pws[2];
  uint32_t pbp[2][4];
#pragma unroll
  for (int it = 0; it < 2; ++it) {
    int idx = t + it * 256, r = idx >> 3, c8 = idx & 7;
    pv[it] = *(const int4*)(Vh + ((size_t)(b * 8 + 0) * 1024 + m0 + r) * 64 + c8 * 8);
    size_t wo = (size_t)(b * 8 + 0) * 1024 + m0 + r;
    pws[it] = Wgp[wo] + Wgp[65536 + wo] + Wgp[2 * 65536 + wo] + Wgp[3 * 65536 + wo] +
              Wgp[4 * 65536 + wo] + Wgp[5 * 65536 + wo] + Wgp[6 * 65536 + wo] +
              Wgp[7 * 65536 + wo];
    const float* wp = Wo + (size_t)(n0 + r) * 512 + c8 * 8;
    float4 f0 = *(const float4*)(wp);
    float4 f1 = *(const float4*)(wp + 4);
    pbp[it][0] = pk2(f0.x, f0.y); pbp[it][1] = pk2(f0.z, f0.w);
    pbp[it][2] = pk2(f1.x, f1.y); pbp[it][3] = pk2(f1.z, f1.w);
  }

  f32x4 acc[4];
#pragma unroll
  for (int j = 0; j < 4; ++j) acc[j] = (f32x4){0.f, 0.f, 0.f, 0.f};

  for (int s = 0; s < 8; ++s) {
    if (s) __syncthreads();
#pragma unroll
    for (int it = 0; it < 2; ++it) {
      int idx = t + it * 256, r = idx >> 3, c8 = idx & 7;
      uint32_t* u = (uint32_t*)&pv[it];
      float ws = pws[it];
      uint32_t o[4];
#pragma unroll
      for (int j = 0; j < 4; ++j) {
        float f0 = __uint_as_float(u[j] << 16) * ws;
        float f1 = __uint_as_float(u[j] & 0xffff0000u) * ws;
        o[j] = pk2(f0, f1);
      }
      *(uint4*)&As[r][c8 * 8] = *(uint4*)o;
      *(uint4*)&Bs[r][c8 * 8] = *(uint4*)pbp[it];
    }
    __syncthreads();
    if (s < 7) {
#pragma unroll
      for (int it = 0; it < 2; ++it) {
        int idx = t + it * 256, r = idx >> 3, c8 = idx & 7;
        pv[it] = *(const int4*)(Vh + ((size_t)(b * 8 + s + 1) * 1024 + m0 + r) * 64 + c8 * 8);
        size_t wo = (size_t)(b * 8 + s + 1) * 1024 + m0 + r;
        pws[it] = Wgp[wo] + Wgp[65536 + wo] + Wgp[2 * 65536 + wo] + Wgp[3 * 65536 + wo] +
                  Wgp[4 * 65536 + wo] + Wgp[5 * 65536 + wo] + Wgp[6 * 65536 + wo] +
                  Wgp[7 * 65536 + wo];
        const float* wp = Wo + (size_t)(n0 + r) * 512 + (s + 1) * 64 + c8 * 8;
        float4 f0 = *(const float4*)(wp);
        float4 f1 = *(const float4*)(wp + 4);
        pbp[it][0] = pk2(f0.x, f0.y); pbp[it][1] = pk2(f0.z, f0.w);
        pbp[it][2] = pk2(f1.x, f1.y); pbp[it][3] = pk2(f1.z, f1.w);
      }
    }

#pragma unroll
    for (int kk = 0; kk < 2; ++kk) {
      bf16x8 a = *(const bf16x8*)&As[wv * 16 + lo][kk * 32 + hi * 8];
#pragma unroll
      for (int fc = 0; fc < 4; ++fc) {
        bf16x8 bfr = *(const bf16x8*)&Bs[fc * 16 + lo][kk * 32 + hi * 8];
        acc[fc] = MFMA(a, bfr, acc[fc]);
      }
    }
  }

#pragma unroll
  for (int fc = 0; fc < 4; ++fc)
#pragma unroll
    for (int r = 0; r < 4; ++r) {
      int i = m0 + wv * 16 + hi * 4 + r;
      int o = n0 + fc * 16 + lo;
      Out[(size_t)(b * 1024 + i) * 256 + o] = acc[fc][r];
    }
}

// ---------------------------------------------------------------------------
extern "C" void kernel_launch(void* const* d_in, const int* in_sizes, int n_in,
                              void* d_out, int out_size, void* d_ws, size_t ws_size,
                              hipStream_t stream) {
  const float* F  = (const float*)d_in[0];
  const float* Wq = (const float*)d_in[1];
  const float* Wk = (const float*)d_in[2];
  const float* Wv = (const float*)d_in[3];
  const float* Wo = (const float*)d_in[4];
  float* out = (float*)d_out;

  char* ws = (char*)d_ws;
  short* Qh  = (short*)(ws);                       // 8 MB bf16
  short* Kh  = (short*)(ws + (size_t)(8  << 20));  // 8 MB
  short* Vh  = (short*)(ws + (size_t)(16 << 20));  // 8 MB
  float* Wgp = (float*)(ws + (size_t)(24 << 20));  // 8 slices x 64bh x 1024 = 2 MB

  k_qkv <<<dim3(512), 256, 0, stream>>>(F, Wq, Wk, Wv, Qh, Kh, Vh);
  k_attw<<<dim3(512), 256, 0, stream>>>(Qh, Kh, Wgp);
  k_out <<<dim3(512), 256, 0, stream>>>(Vh, Wgp, Wo, out);
}